// Round 1
// baseline (432.537 us; speedup 1.0000x reference)
//
#include <hip/hip_runtime.h>
#include <cstdint>
#include <cstddef>

#define B_ROWS 8192
#define IN_DIM 2048
#define OUT_DIM 2048
#define STY_DIM 512

#define BM 128
#define BN 128
#define BK 32
#define PAD_K 40   // bf16 elems per LDS row: 32 data + 8 pad -> 80 B row stride (16B aligned)

typedef unsigned short u16;
typedef __attribute__((ext_vector_type(8))) short bf16x8;
typedef __attribute__((ext_vector_type(4))) float f32x4;

// Split fp32 pair -> packed bf16 hi-pair and lo-pair (truncation split; residual ~2^-16 rel).
__device__ __forceinline__ void cvt_pair(float x0, float x1, uint32_t& hi, uint32_t& lo) {
  uint32_t u0 = __float_as_uint(x0), u1 = __float_as_uint(x1);
  uint32_t a0 = u0 & 0xffff0000u, a1 = u1 & 0xffff0000u;
  hi = (u0 >> 16) | a1;
  float l0 = x0 - __uint_as_float(a0);
  float l1 = x1 - __uint_as_float(a1);
  lo = (__float_as_uint(l0) >> 16) | (__float_as_uint(l1) & 0xffff0000u);
}

__device__ __forceinline__ void write_rep(const float4& v, u16* baseHi, u16* baseLo) {
  uint32_t h0, h1, l0, l1;
  cvt_pair(v.x, v.y, h0, l0);
  cvt_pair(v.z, v.w, h1, l1);
  uint2 hw; hw.x = h0; hw.y = h1;
  uint2 lw; lw.x = l0; lw.y = l1;
  *reinterpret_cast<uint2*>(baseHi) = hw;   // 8B ds_write, 8B-aligned
  *reinterpret_cast<uint2*>(baseLo) = lw;
}

// One GEMM phase: acc += A(128xK) * B(128xK)^T over K = NT*BK, split-bf16 3-term MFMA.
// gA points at (brow, 0), gB at (bcol, 0); both row-major with leading dim LDK.
template<int LDK, int NT>
__device__ __forceinline__ void gemm_phase(
    const float* __restrict__ gA, const float* __restrict__ gB,
    f32x4 (&acc)[4][4],
    u16* sAhi, u16* sAlo, u16* sBhi, u16* sBlo,
    int tid)
{
  // staging: 256 threads, thread covers 4 consecutive fp32; 4 reps per 128x32 tile
  const int sr = tid >> 3;            // row within a 32-row rep
  const int sk = (tid & 7) * 4;       // k offset 0..28
  const float* pa = gA + (size_t)sr * LDK + sk;
  const float* pb = gB + (size_t)sr * LDK + sk;
  const int lbase = sr * PAD_K + sk;  // u16 units

  const int lane = tid & 63;
  const int wid  = tid >> 6;
  const int wr = wid >> 1, wc = wid & 1;   // 2x2 wave grid, 64x64 per wave
  const int fr = lane & 15;
  const int kg = lane >> 4;
  const int aoff = (wr * 64 + fr) * PAD_K + kg * 8;
  const int boff = (wc * 64 + fr) * PAD_K + kg * 8;

  float4 va[4], vb[4];
  #pragma unroll
  for (int rep = 0; rep < 4; ++rep) {
    va[rep] = *reinterpret_cast<const float4*>(pa + (size_t)rep * 32 * LDK);
    vb[rep] = *reinterpret_cast<const float4*>(pb + (size_t)rep * 32 * LDK);
  }
  pa += BK; pb += BK;

  for (int t = 0; t < NT; ++t) {
    __syncthreads();   // all waves done READING previous tile
    #pragma unroll
    for (int rep = 0; rep < 4; ++rep) {
      write_rep(va[rep], sAhi + lbase + rep * 32 * PAD_K, sAlo + lbase + rep * 32 * PAD_K);
      write_rep(vb[rep], sBhi + lbase + rep * 32 * PAD_K, sBlo + lbase + rep * 32 * PAD_K);
    }
    __syncthreads();   // tile t visible
    if (t + 1 < NT) {  // issue next-tile loads early; latency hides under MFMA below
      #pragma unroll
      for (int rep = 0; rep < 4; ++rep) {
        va[rep] = *reinterpret_cast<const float4*>(pa + (size_t)rep * 32 * LDK);
        vb[rep] = *reinterpret_cast<const float4*>(pb + (size_t)rep * 32 * LDK);
      }
      pa += BK; pb += BK;
    }

    bf16x8 bhi[4], blo[4];
    #pragma unroll
    for (int nj = 0; nj < 4; ++nj) {
      bhi[nj] = *reinterpret_cast<const bf16x8*>(sBhi + boff + nj * 16 * PAD_K);
      blo[nj] = *reinterpret_cast<const bf16x8*>(sBlo + boff + nj * 16 * PAD_K);
    }
    #pragma unroll
    for (int mi = 0; mi < 4; ++mi) {
      bf16x8 ahi = *reinterpret_cast<const bf16x8*>(sAhi + aoff + mi * 16 * PAD_K);
      bf16x8 alo = *reinterpret_cast<const bf16x8*>(sAlo + aoff + mi * 16 * PAD_K);
      #pragma unroll
      for (int nj = 0; nj < 4; ++nj) {
        acc[mi][nj] = __builtin_amdgcn_mfma_f32_16x16x32_bf16(ahi, bhi[nj], acc[mi][nj], 0, 0, 0);
        acc[mi][nj] = __builtin_amdgcn_mfma_f32_16x16x32_bf16(ahi, blo[nj], acc[mi][nj], 0, 0, 0);
        acc[mi][nj] = __builtin_amdgcn_mfma_f32_16x16x32_bf16(alo, bhi[nj], acc[mi][nj], 0, 0, 0);
      }
    }
  }
  __syncthreads();  // protect LDS before next phase overwrites
}

__global__ void rowsq_kernel(const float* __restrict__ w, float* __restrict__ srq) {
  int row  = blockIdx.x * 4 + (threadIdx.x >> 6);
  int lane = threadIdx.x & 63;
  const float4* p = reinterpret_cast<const float4*>(w + (size_t)row * IN_DIM);
  float s = 0.f;
  #pragma unroll
  for (int i = 0; i < 8; ++i) {
    float4 v = p[lane + i * 64];
    s += v.x * v.x + v.y * v.y + v.z * v.z + v.w * v.w;
  }
  #pragma unroll
  for (int off = 32; off > 0; off >>= 1) s += __shfl_down(s, off);
  if (lane == 0) srq[row] = sqrtf(s);
}

__global__ __launch_bounds__(256, 2) void fused_style_linear(
    const float* __restrict__ input, const float* __restrict__ style,
    const float* __restrict__ weight, const float* __restrict__ bias,
    const float* __restrict__ aff_w, const float* __restrict__ aff_b,
    const float* __restrict__ srq, float* __restrict__ out)
{
  __shared__ u16 sAhi[BM * PAD_K];
  __shared__ u16 sAlo[BM * PAD_K];
  __shared__ u16 sBhi[BN * PAD_K];
  __shared__ u16 sBlo[BN * PAD_K];

  const int tid = threadIdx.x;
  const int bn = blockIdx.x, bm = blockIdx.y;
  const int brow = bm * BM, bcol = bn * BN;

  const int lane = tid & 63, wid = tid >> 6;
  const int wr = wid >> 1, wc = wid & 1;
  const int fr = lane & 15, kg = lane >> 4;

  // ---- Phase 1: scale = style @ aff_w[:OUT].T  (K = 512) ----
  f32x4 sacc[4][4];
  #pragma unroll
  for (int i = 0; i < 4; ++i)
    #pragma unroll
    for (int j = 0; j < 4; ++j) {
      f32x4 z = {0.f, 0.f, 0.f, 0.f};
      sacc[i][j] = z;
    }

  gemm_phase<STY_DIM, STY_DIM / BK>(style + (size_t)brow * STY_DIM,
                                    aff_w + (size_t)bcol * STY_DIM,
                                    sacc, sAhi, sAlo, sBhi, sBlo, tid);

  // per-column constants for this thread's 4 fragment columns
  float affb[4], srqv[4], biasv[4];
  #pragma unroll
  for (int nj = 0; nj < 4; ++nj) {
    int c = bcol + wc * 64 + nj * 16 + fr;
    affb[nj]  = aff_b[c];
    srqv[nj]  = srq[c];
    biasv[nj] = bias[c];
  }

  // mod = s * |s| * sqrt(rowsq), computed in-place in sacc
  #pragma unroll
  for (int mi = 0; mi < 4; ++mi)
    #pragma unroll
    for (int nj = 0; nj < 4; ++nj)
      #pragma unroll
      for (int r = 0; r < 4; ++r) {
        float s = sacc[mi][nj][r] + affb[nj];
        sacc[mi][nj][r] = s * fabsf(s) * srqv[nj];
      }

  // ---- Phase 2: base = input @ weight.T  (K = 2048) ----
  f32x4 acc[4][4];
  #pragma unroll
  for (int i = 0; i < 4; ++i)
    #pragma unroll
    for (int j = 0; j < 4; ++j) {
      f32x4 z = {0.f, 0.f, 0.f, 0.f};
      acc[i][j] = z;
    }

  gemm_phase<IN_DIM, IN_DIM / BK>(input + (size_t)brow * IN_DIM,
                                  weight + (size_t)bcol * IN_DIM,
                                  acc, sAhi, sAlo, sBhi, sBlo, tid);

  // ---- Epilogue: out = base * mod + bias ----
  #pragma unroll
  for (int mi = 0; mi < 4; ++mi) {
    int r0 = brow + wr * 64 + mi * 16 + kg * 4;
    #pragma unroll
    for (int nj = 0; nj < 4; ++nj) {
      int c = bcol + wc * 64 + nj * 16 + fr;
      float* po = out + (size_t)r0 * OUT_DIM + c;
      #pragma unroll
      for (int r = 0; r < 4; ++r) {
        po[(size_t)r * OUT_DIM] = acc[mi][nj][r] * sacc[mi][nj][r] + biasv[nj];
      }
    }
  }
}

extern "C" void kernel_launch(void* const* d_in, const int* in_sizes, int n_in,
                              void* d_out, int out_size, void* d_ws, size_t ws_size,
                              hipStream_t stream) {
  (void)in_sizes; (void)n_in; (void)out_size; (void)ws_size;
  const float* input  = (const float*)d_in[0];
  const float* style  = (const float*)d_in[1];
  const float* weight = (const float*)d_in[2];
  const float* bias   = (const float*)d_in[3];
  const float* aff_w  = (const float*)d_in[4];
  const float* aff_b  = (const float*)d_in[5];
  float* out = (float*)d_out;
  float* srq = (float*)d_ws;   // 2048 floats = 8 KiB scratch

  rowsq_kernel<<<OUT_DIM / 4, 256, 0, stream>>>(weight, srq);

  dim3 grid(OUT_DIM / BN, B_ROWS / BM);
  fused_style_linear<<<grid, 256, 0, stream>>>(input, style, weight, bias,
                                               aff_w, aff_b, srq, out);
}

// Round 3
// 393.678 us; speedup vs baseline: 1.0987x; 1.0987x over previous
//
#include <hip/hip_runtime.h>
#include <cstdint>
#include <cstddef>

#define B_ROWS 8192
#define IN_DIM 2048
#define OUT_DIM 2048
#define STY_DIM 512

typedef unsigned short u16;
typedef __attribute__((ext_vector_type(8))) short bf16x8;
typedef __attribute__((ext_vector_type(4))) float f32x4;

// Split fp32 pair -> packed bf16 hi-pair and lo-pair (truncation split; residual ~2^-16 rel).
__device__ __forceinline__ void cvt_pair(float x0, float x1, uint32_t& hi, uint32_t& lo) {
  uint32_t u0 = __float_as_uint(x0), u1 = __float_as_uint(x1);
  uint32_t a0 = u0 & 0xffff0000u, a1 = u1 & 0xffff0000u;
  hi = (u0 >> 16) | a1;
  float l0 = x0 - __uint_as_float(a0);
  float l1 = x1 - __uint_as_float(a1);
  lo = (__float_as_uint(l0) >> 16) | (__float_as_uint(l1) & 0xffff0000u);
}

// ============================ fast path =================================

// Elementwise fp32 -> (bf16 hi, bf16 lo) split, float4-vectorized, grid-stride.
__global__ void split_kernel(const float* __restrict__ src,
                             u16* __restrict__ hi, u16* __restrict__ lo, int n4) {
  int stride = gridDim.x * blockDim.x;
  for (int i = blockIdx.x * blockDim.x + threadIdx.x; i < n4; i += stride) {
    float4 v = reinterpret_cast<const float4*>(src)[i];
    uint32_t h0, h1, l0, l1;
    cvt_pair(v.x, v.y, h0, l0);
    cvt_pair(v.z, v.w, h1, l1);
    uint2 hw; hw.x = h0; hw.y = h1;
    uint2 lw; lw.x = l0; lw.y = l1;
    reinterpret_cast<uint2*>(hi)[i] = hw;
    reinterpret_cast<uint2*>(lo)[i] = lw;
  }
}

__global__ void rowsq_kernel(const float* __restrict__ w, float* __restrict__ srq) {
  int row  = blockIdx.x * 4 + (threadIdx.x >> 6);
  int lane = threadIdx.x & 63;
  const float4* p = reinterpret_cast<const float4*>(w + (size_t)row * IN_DIM);
  float s = 0.f;
  #pragma unroll
  for (int i = 0; i < 8; ++i) {
    float4 v = p[lane + i * 64];
    s += v.x * v.x + v.y * v.y + v.z * v.z + v.w * v.w;
  }
  #pragma unroll
  for (int off = 32; off > 0; off >>= 1) s += __shfl_down(s, off);
  if (lane == 0) srq[row] = sqrtf(s);
}

// Pure-bf16 GEMM phase, m97 structure: global_load_lds(16B) staging, linear
// 64B LDS rows, 2 barriers per K-step, 48 MFMA : 16 ds_read_b128 per step.
// acc += A(128xK) * B(128xK)^T ; all four g* pointers are at (row0, k=0),
// row-major bf16 with leading dim LDK (u16 elements).
template<int LDK, int NT>
__device__ __forceinline__ void gemm_bf16_phase(
    const u16* __restrict__ gAhi, const u16* __restrict__ gAlo,
    const u16* __restrict__ gBhi, const u16* __restrict__ gBlo,
    f32x4 (&acc)[4][4],
    u16* sAhi, u16* sAlo, u16* sBhi, u16* sBlo,
    int tid)
{
  const int lane = tid & 63;
  const int wid  = tid >> 6;
  const int wr = wid >> 1, wc = wid & 1;
  const int fr = lane & 15, kg = lane >> 4;

  // wave w stages one 128x32 tile: {0:Ahi, 1:Alo, 2:Bhi, 3:Blo}
  const u16* gsrc = (wid == 0) ? gAhi : (wid == 1) ? gAlo : (wid == 2) ? gBhi : gBlo;
  u16* sdst = (wid == 0) ? sAhi : (wid == 1) ? sAlo : (wid == 2) ? sBhi : sBlo;
  // lane -> (row = lane>>2 within 16-row stripe, 16B chunk = lane&3)
  const u16* gl = gsrc + (size_t)(lane >> 2) * LDK + (size_t)(lane & 3) * 8;

  const int aoff = (wr * 64 + fr) * 32 + kg * 8;   // u16 offset in [128][32] tile
  const int boff = (wc * 64 + fr) * 32 + kg * 8;

  for (int t = 0; t < NT; ++t) {
    __syncthreads();                       // everyone done reading previous tile
    {
      const u16* g = gl + t * 32;
      #pragma unroll
      for (int i = 0; i < 8; ++i) {        // 8 x (64 lanes x 16B) = 8 KiB tile
        __builtin_amdgcn_global_load_lds(
            (const __attribute__((address_space(1))) void*)(g),
            (__attribute__((address_space(3))) void*)(sdst + i * 512),
            16, 0, 0);
        g += (size_t)16 * LDK;
      }
    }
    __syncthreads();                       // vmcnt(0) drained before barrier -> tile visible

    bf16x8 bh[4], bl[4];
    #pragma unroll
    for (int nj = 0; nj < 4; ++nj) {
      bh[nj] = *reinterpret_cast<const bf16x8*>(sBhi + boff + nj * 16 * 32);
      bl[nj] = *reinterpret_cast<const bf16x8*>(sBlo + boff + nj * 16 * 32);
    }
    #pragma unroll
    for (int mi = 0; mi < 4; ++mi) {
      bf16x8 ah = *reinterpret_cast<const bf16x8*>(sAhi + aoff + mi * 16 * 32);
      bf16x8 al = *reinterpret_cast<const bf16x8*>(sAlo + aoff + mi * 16 * 32);
      #pragma unroll
      for (int nj = 0; nj < 4; ++nj) {
        acc[mi][nj] = __builtin_amdgcn_mfma_f32_16x16x32_bf16(ah, bh[nj], acc[mi][nj], 0, 0, 0);
        acc[mi][nj] = __builtin_amdgcn_mfma_f32_16x16x32_bf16(ah, bl[nj], acc[mi][nj], 0, 0, 0);
        acc[mi][nj] = __builtin_amdgcn_mfma_f32_16x16x32_bf16(al, bh[nj], acc[mi][nj], 0, 0, 0);
      }
    }
  }
}

__global__ __launch_bounds__(256, 2) void fused_fast(
    const u16* __restrict__ ihi, const u16* __restrict__ ilo,
    const u16* __restrict__ whi, const u16* __restrict__ wlo,
    const u16* __restrict__ shi, const u16* __restrict__ slo,
    const u16* __restrict__ awhi, const u16* __restrict__ awlo,
    const float* __restrict__ bias, const float* __restrict__ aff_b,
    const float* __restrict__ srq, float* __restrict__ out)
{
  __shared__ u16 sAhi[128 * 32];
  __shared__ u16 sAlo[128 * 32];
  __shared__ u16 sBhi[128 * 32];
  __shared__ u16 sBlo[128 * 32];

  const int tid = threadIdx.x;
  const int bn = blockIdx.x, bm = blockIdx.y;
  const int brow = bm * 128, bcol = bn * 128;
  const int lane = tid & 63, wid = tid >> 6;
  const int wr = wid >> 1, wc = wid & 1;
  const int fr = lane & 15, kg = lane >> 4;

  // ---- Phase 1: scale = style @ aff_w[:OUT].T  (K = 512) ----
  f32x4 sacc[4][4];
  #pragma unroll
  for (int i = 0; i < 4; ++i)
    #pragma unroll
    for (int j = 0; j < 4; ++j) {
      f32x4 z = {0.f, 0.f, 0.f, 0.f};
      sacc[i][j] = z;
    }

  gemm_bf16_phase<STY_DIM, STY_DIM / 32>(
      shi + (size_t)brow * STY_DIM, slo + (size_t)brow * STY_DIM,
      awhi + (size_t)bcol * STY_DIM, awlo + (size_t)bcol * STY_DIM,
      sacc, sAhi, sAlo, sBhi, sBlo, tid);

  float affb[4], srqv[4], biasv[4];
  #pragma unroll
  for (int nj = 0; nj < 4; ++nj) {
    int c = bcol + wc * 64 + nj * 16 + fr;
    affb[nj]  = aff_b[c];
    srqv[nj]  = srq[c];
    biasv[nj] = bias[c];
  }

  // mod = s * |s| * sqrt(rowsq)
  #pragma unroll
  for (int mi = 0; mi < 4; ++mi)
    #pragma unroll
    for (int nj = 0; nj < 4; ++nj)
      #pragma unroll
      for (int r = 0; r < 4; ++r) {
        float s = sacc[mi][nj][r] + affb[nj];
        sacc[mi][nj][r] = s * fabsf(s) * srqv[nj];
      }

  // ---- Phase 2: base = input @ weight.T  (K = 2048) ----
  f32x4 acc[4][4];
  #pragma unroll
  for (int i = 0; i < 4; ++i)
    #pragma unroll
    for (int j = 0; j < 4; ++j) {
      f32x4 z = {0.f, 0.f, 0.f, 0.f};
      acc[i][j] = z;
    }

  gemm_bf16_phase<IN_DIM, IN_DIM / 32>(
      ihi + (size_t)brow * IN_DIM, ilo + (size_t)brow * IN_DIM,
      whi + (size_t)bcol * IN_DIM, wlo + (size_t)bcol * IN_DIM,
      acc, sAhi, sAlo, sBhi, sBlo, tid);

  // ---- Epilogue: out = base * mod + bias ----
  #pragma unroll
  for (int mi = 0; mi < 4; ++mi) {
    int r0 = brow + wr * 64 + mi * 16 + kg * 4;
    #pragma unroll
    for (int nj = 0; nj < 4; ++nj) {
      int c = bcol + wc * 64 + nj * 16 + fr;
      float* po = out + (size_t)r0 * OUT_DIM + c;
      #pragma unroll
      for (int r = 0; r < 4; ++r) {
        po[(size_t)r * OUT_DIM] = acc[mi][nj][r] * sacc[mi][nj][r] + biasv[nj];
      }
    }
  }
}

// ======================= fallback path (R1 kernel) ======================

#define BMf 128
#define BNf 128
#define BKf 32
#define PAD_K 40

__device__ __forceinline__ void write_rep(const float4& v, u16* baseHi, u16* baseLo) {
  uint32_t h0, h1, l0, l1;
  cvt_pair(v.x, v.y, h0, l0);
  cvt_pair(v.z, v.w, h1, l1);
  uint2 hw; hw.x = h0; hw.y = h1;
  uint2 lw; lw.x = l0; lw.y = l1;
  *reinterpret_cast<uint2*>(baseHi) = hw;
  *reinterpret_cast<uint2*>(baseLo) = lw;
}

template<int LDK, int NT>
__device__ __forceinline__ void gemm_phase(
    const float* __restrict__ gA, const float* __restrict__ gB,
    f32x4 (&acc)[4][4],
    u16* sAhi, u16* sAlo, u16* sBhi, u16* sBlo,
    int tid)
{
  const int sr = tid >> 3;
  const int sk = (tid & 7) * 4;
  const float* pa = gA + (size_t)sr * LDK + sk;
  const float* pb = gB + (size_t)sr * LDK + sk;
  const int lbase = sr * PAD_K + sk;

  const int lane = tid & 63;
  const int wid  = tid >> 6;
  const int wr = wid >> 1, wc = wid & 1;
  const int fr = lane & 15;
  const int kg = lane >> 4;
  const int aoff = (wr * 64 + fr) * PAD_K + kg * 8;
  const int boff = (wc * 64 + fr) * PAD_K + kg * 8;

  float4 va[4], vb[4];
  #pragma unroll
  for (int rep = 0; rep < 4; ++rep) {
    va[rep] = *reinterpret_cast<const float4*>(pa + (size_t)rep * 32 * LDK);
    vb[rep] = *reinterpret_cast<const float4*>(pb + (size_t)rep * 32 * LDK);
  }
  pa += BKf; pb += BKf;

  for (int t = 0; t < NT; ++t) {
    __syncthreads();
    #pragma unroll
    for (int rep = 0; rep < 4; ++rep) {
      write_rep(va[rep], sAhi + lbase + rep * 32 * PAD_K, sAlo + lbase + rep * 32 * PAD_K);
      write_rep(vb[rep], sBhi + lbase + rep * 32 * PAD_K, sBlo + lbase + rep * 32 * PAD_K);
    }
    __syncthreads();
    if (t + 1 < NT) {
      #pragma unroll
      for (int rep = 0; rep < 4; ++rep) {
        va[rep] = *reinterpret_cast<const float4*>(pa + (size_t)rep * 32 * LDK);
        vb[rep] = *reinterpret_cast<const float4*>(pb + (size_t)rep * 32 * LDK);
      }
      pa += BKf; pb += BKf;
    }

    bf16x8 bhi[4], blo[4];
    #pragma unroll
    for (int nj = 0; nj < 4; ++nj) {
      bhi[nj] = *reinterpret_cast<const bf16x8*>(sBhi + boff + nj * 16 * PAD_K);
      blo[nj] = *reinterpret_cast<const bf16x8*>(sBlo + boff + nj * 16 * PAD_K);
    }
    #pragma unroll
    for (int mi = 0; mi < 4; ++mi) {
      bf16x8 ahi = *reinterpret_cast<const bf16x8*>(sAhi + aoff + mi * 16 * PAD_K);
      bf16x8 alo = *reinterpret_cast<const bf16x8*>(sAlo + aoff + mi * 16 * PAD_K);
      #pragma unroll
      for (int nj = 0; nj < 4; ++nj) {
        acc[mi][nj] = __builtin_amdgcn_mfma_f32_16x16x32_bf16(ahi, bhi[nj], acc[mi][nj], 0, 0, 0);
        acc[mi][nj] = __builtin_amdgcn_mfma_f32_16x16x32_bf16(ahi, blo[nj], acc[mi][nj], 0, 0, 0);
        acc[mi][nj] = __builtin_amdgcn_mfma_f32_16x16x32_bf16(alo, bhi[nj], acc[mi][nj], 0, 0, 0);
      }
    }
  }
  __syncthreads();
}

__global__ __launch_bounds__(256, 2) void fused_style_linear(
    const float* __restrict__ input, const float* __restrict__ style,
    const float* __restrict__ weight, const float* __restrict__ bias,
    const float* __restrict__ aff_w, const float* __restrict__ aff_b,
    const float* __restrict__ srq, float* __restrict__ out)
{
  __shared__ u16 sAhi[BMf * PAD_K];
  __shared__ u16 sAlo[BMf * PAD_K];
  __shared__ u16 sBhi[BNf * PAD_K];
  __shared__ u16 sBlo[BNf * PAD_K];

  const int tid = threadIdx.x;
  const int bn = blockIdx.x, bm = blockIdx.y;
  const int brow = bm * BMf, bcol = bn * BNf;

  const int lane = tid & 63, wid = tid >> 6;
  const int wr = wid >> 1, wc = wid & 1;
  const int fr = lane & 15, kg = lane >> 4;

  f32x4 sacc[4][4];
  #pragma unroll
  for (int i = 0; i < 4; ++i)
    #pragma unroll
    for (int j = 0; j < 4; ++j) {
      f32x4 z = {0.f, 0.f, 0.f, 0.f};
      sacc[i][j] = z;
    }

  gemm_phase<STY_DIM, STY_DIM / BKf>(style + (size_t)brow * STY_DIM,
                                     aff_w + (size_t)bcol * STY_DIM,
                                     sacc, sAhi, sAlo, sBhi, sBlo, tid);

  float affb[4], srqv[4], biasv[4];
  #pragma unroll
  for (int nj = 0; nj < 4; ++nj) {
    int c = bcol + wc * 64 + nj * 16 + fr;
    affb[nj]  = aff_b[c];
    srqv[nj]  = srq[c];
    biasv[nj] = bias[c];
  }

  #pragma unroll
  for (int mi = 0; mi < 4; ++mi)
    #pragma unroll
    for (int nj = 0; nj < 4; ++nj)
      #pragma unroll
      for (int r = 0; r < 4; ++r) {
        float s = sacc[mi][nj][r] + affb[nj];
        sacc[mi][nj][r] = s * fabsf(s) * srqv[nj];
      }

  f32x4 acc[4][4];
  #pragma unroll
  for (int i = 0; i < 4; ++i)
    #pragma unroll
    for (int j = 0; j < 4; ++j) {
      f32x4 z = {0.f, 0.f, 0.f, 0.f};
      acc[i][j] = z;
    }

  gemm_phase<IN_DIM, IN_DIM / BKf>(input + (size_t)brow * IN_DIM,
                                   weight + (size_t)bcol * IN_DIM,
                                   acc, sAhi, sAlo, sBhi, sBlo, tid);

  #pragma unroll
  for (int mi = 0; mi < 4; ++mi) {
    int r0 = brow + wr * 64 + mi * 16 + kg * 4;
    #pragma unroll
    for (int nj = 0; nj < 4; ++nj) {
      int c = bcol + wc * 64 + nj * 16 + fr;
      float* po = out + (size_t)r0 * OUT_DIM + c;
      #pragma unroll
      for (int r = 0; r < 4; ++r) {
        po[(size_t)r * OUT_DIM] = acc[mi][nj][r] * sacc[mi][nj][r] + biasv[nj];
      }
    }
  }
}

// ============================== launch ==================================

extern "C" void kernel_launch(void* const* d_in, const int* in_sizes, int n_in,
                              void* d_out, int out_size, void* d_ws, size_t ws_size,
                              hipStream_t stream) {
  (void)in_sizes; (void)n_in; (void)out_size;
  const float* input  = (const float*)d_in[0];
  const float* style  = (const float*)d_in[1];
  const float* weight = (const float*)d_in[2];
  const float* bias   = (const float*)d_in[3];
  const float* aff_w  = (const float*)d_in[4];
  const float* aff_b  = (const float*)d_in[5];
  float* out = (float*)d_out;

  // ws layout (bytes)
  const size_t OFF_IHI = 0;
  const size_t OFF_ILO = OFF_IHI + (size_t)B_ROWS * IN_DIM * 2;    // 32 MiB each
  const size_t OFF_WHI = OFF_ILO + (size_t)B_ROWS * IN_DIM * 2;
  const size_t OFF_WLO = OFF_WHI + (size_t)OUT_DIM * IN_DIM * 2;   // 8 MiB each
  const size_t OFF_SHI = OFF_WLO + (size_t)OUT_DIM * IN_DIM * 2;
  const size_t OFF_SLO = OFF_SHI + (size_t)B_ROWS * STY_DIM * 2;   // 8 MiB each
  const size_t OFF_AHI = OFF_SLO + (size_t)B_ROWS * STY_DIM * 2;
  const size_t OFF_ALO = OFF_AHI + (size_t)OUT_DIM * STY_DIM * 2;  // 2 MiB each
  const size_t OFF_SRQ = OFF_ALO + (size_t)OUT_DIM * STY_DIM * 2;
  const size_t WS_NEEDED = OFF_SRQ + OUT_DIM * 4;

  if (ws_size >= WS_NEEDED) {
    char* ws = (char*)d_ws;
    u16* ihi = (u16*)(ws + OFF_IHI);
    u16* ilo = (u16*)(ws + OFF_ILO);
    u16* whi = (u16*)(ws + OFF_WHI);
    u16* wlo = (u16*)(ws + OFF_WLO);
    u16* shi = (u16*)(ws + OFF_SHI);
    u16* slo = (u16*)(ws + OFF_SLO);
    u16* awhi = (u16*)(ws + OFF_AHI);
    u16* awlo = (u16*)(ws + OFF_ALO);
    float* srq = (float*)(ws + OFF_SRQ);

    split_kernel<<<2048, 256, 0, stream>>>(input,  ihi,  ilo,  B_ROWS * IN_DIM / 4);
    split_kernel<<<2048, 256, 0, stream>>>(weight, whi,  wlo,  OUT_DIM * IN_DIM / 4);
    split_kernel<<<2048, 256, 0, stream>>>(style,  shi,  slo,  B_ROWS * STY_DIM / 4);
    split_kernel<<<1024, 256, 0, stream>>>(aff_w,  awhi, awlo, OUT_DIM * STY_DIM / 4);
    rowsq_kernel<<<OUT_DIM / 4, 256, 0, stream>>>(weight, srq);

    dim3 grid(OUT_DIM / 128, B_ROWS / 128);
    fused_fast<<<grid, 256, 0, stream>>>(ihi, ilo, whi, wlo, shi, slo, awhi, awlo,
                                         bias, aff_b, srq, out);
  } else {
    float* srq = (float*)d_ws;  // 8 KiB
    rowsq_kernel<<<OUT_DIM / 4, 256, 0, stream>>>(weight, srq);
    dim3 grid(OUT_DIM / BNf, B_ROWS / BMf);
    fused_style_linear<<<grid, 256, 0, stream>>>(input, style, weight, bias,
                                                 aff_w, aff_b, srq, out);
  }
}